// Round 1
// baseline (129.394 us; speedup 1.0000x reference)
//
#include <hip/hip_runtime.h>

// Fused causal single-head attention for B=256, T=512, C=HS=64 (fp32 in/out).
// One block per batch element; K and V^T live in LDS; flash-style online
// softmax; all matmuls via v_mfma_f32_16x16x32_bf16 with guide-verified
// fragment layouts:
//   A: lane holds A[m=lane&15][k=(lane>>4)*8+j]
//   B: lane holds B[k=(lane>>4)*8+j][n=lane&15]
//   C/D: lane holds D[row=(lane>>4)*4+r][col=lane&15]

#define BATCH 256
#define SEQ   512
#define CH    64
#define HSZ   64

#define KPAD 72    // K row stride (ushorts): 64 + 8 pad -> 2-way bank aliasing (free)
#define VPAD 520   // V^T row stride (ushorts): 512 + 8 pad
#define PPAD 72    // per-wave transpose buffer row stride (ushorts)

typedef __attribute__((ext_vector_type(8))) short bf16x8;
typedef __attribute__((ext_vector_type(4))) float f32x4;

static __device__ __forceinline__ short f2bf(float f) {
  union { float f; unsigned u; } v; v.f = f;
  unsigned r = v.u + 0x7FFFu + ((v.u >> 16) & 1u);   // RNE
  return (short)(r >> 16);
}

static __device__ __forceinline__ void lds_fence() {
  // order LDS write->read (and read->write reuse) within the wave
  asm volatile("s_waitcnt lgkmcnt(0)" ::: "memory");
}

__global__ __launch_bounds__(512, 2)
void attn_fused(const float* __restrict__ x,
                const float* __restrict__ wk,
                const float* __restrict__ wq,
                const float* __restrict__ wv,
                float* __restrict__ out) {
  __shared__ alignas(16) unsigned short ldsK[SEQ * KPAD];      // K  [t][ch]
  __shared__ alignas(16) unsigned short ldsV[HSZ * VPAD];      // Vt [ch][t]
  __shared__ alignas(16) unsigned short ldsP[8 * 16 * PPAD];   // per-wave 16x64

  const int b    = blockIdx.x;
  const int w    = threadIdx.x >> 6;   // wave 0..7
  const int lane = threadIdx.x & 63;
  const int l15  = lane & 15;
  const int quad = lane >> 4;          // 0..3

  const float* xb   = x + (size_t)b * SEQ * CH;
  float*       outb = out + (size_t)b * SEQ * HSZ;

  // ---- weight B-fragments (held in registers for the whole kernel) ----
  // frag[nt][c]: lane holds W[k = c*32 + quad*8 + j][n = nt*16 + l15]
  bf16x8 WK[4][2], WV[4][2], WQ[4][2];
#pragma unroll
  for (int nt = 0; nt < 4; ++nt)
#pragma unroll
    for (int c = 0; c < 2; ++c) {
      const int k0 = c * 32 + quad * 8;
      const int n  = nt * 16 + l15;
      bf16x8 fk, fv, fq;
#pragma unroll
      for (int j = 0; j < 8; ++j) {
        fk[j] = f2bf(wk[(k0 + j) * HSZ + n]);
        fv[j] = f2bf(wv[(k0 + j) * HSZ + n]);
        fq[j] = f2bf(wq[(k0 + j) * HSZ + n] * 0.125f);  // fold C^-0.5 into Wq
      }
      WK[nt][c] = fk; WV[nt][c] = fv; WQ[nt][c] = fq;
    }

  // ---- phase 1: K and V^T (bf16) into LDS; wave w owns tokens [w*64, w*64+64) ----
#pragma unroll 1
  for (int s = 0; s < 4; ++s) {
    const int t0 = w * 64 + s * 16;
    bf16x8 xa[2];
#pragma unroll
    for (int c = 0; c < 2; ++c) {
      const float* px = xb + (t0 + l15) * CH + c * 32 + quad * 8;
      float4 lo = *(const float4*)px;
      float4 hi = *(const float4*)(px + 4);
      bf16x8 f;
      f[0] = f2bf(lo.x); f[1] = f2bf(lo.y); f[2] = f2bf(lo.z); f[3] = f2bf(lo.w);
      f[4] = f2bf(hi.x); f[5] = f2bf(hi.y); f[6] = f2bf(hi.z); f[7] = f2bf(hi.w);
      xa[c] = f;
    }
#pragma unroll
    for (int nt = 0; nt < 4; ++nt) {
      f32x4 ak = {0.f, 0.f, 0.f, 0.f};
      f32x4 av = {0.f, 0.f, 0.f, 0.f};
#pragma unroll
      for (int c = 0; c < 2; ++c) {
        ak = __builtin_amdgcn_mfma_f32_16x16x32_bf16(xa[c], WK[nt][c], ak, 0, 0, 0);
        av = __builtin_amdgcn_mfma_f32_16x16x32_bf16(xa[c], WV[nt][c], av, 0, 0, 0);
      }
      const int col = nt * 16 + l15;
#pragma unroll
      for (int r = 0; r < 4; ++r) {
        const int row = t0 + quad * 4 + r;
        ldsK[row * KPAD + col] = (unsigned short)f2bf(ak[r]);
        ldsV[col * VPAD + row] = (unsigned short)f2bf(av[r]);   // transposed store
      }
    }
  }
  __syncthreads();   // the only block-wide barrier

  // ---- phase 2: flash attention; wave w owns strips {w, 15-w, 16+w, 31-w} ----
  unsigned short* pw = ldsP + w * 16 * PPAD;
#pragma unroll 1
  for (int si = 0; si < 4; ++si) {
    const int base16 = (si & 2) * 8;                      // 0,0,16,16
    const int strip  = (si & 1) ? (15 - w + base16) : (w + base16);
    const int q0     = strip * 16;

    // Q = (x @ Wq) * 0.125, computed as C-frags then transposed to A-frags via LDS
    bf16x8 xa[2];
#pragma unroll
    for (int c = 0; c < 2; ++c) {
      const float* px = xb + (q0 + l15) * CH + c * 32 + quad * 8;
      float4 lo = *(const float4*)px;
      float4 hi = *(const float4*)(px + 4);
      bf16x8 f;
      f[0] = f2bf(lo.x); f[1] = f2bf(lo.y); f[2] = f2bf(lo.z); f[3] = f2bf(lo.w);
      f[4] = f2bf(hi.x); f[5] = f2bf(hi.y); f[6] = f2bf(hi.z); f[7] = f2bf(hi.w);
      xa[c] = f;
    }
#pragma unroll
    for (int nt = 0; nt < 4; ++nt) {
      f32x4 aq = {0.f, 0.f, 0.f, 0.f};
#pragma unroll
      for (int c = 0; c < 2; ++c)
        aq = __builtin_amdgcn_mfma_f32_16x16x32_bf16(xa[c], WQ[nt][c], aq, 0, 0, 0);
#pragma unroll
      for (int r = 0; r < 4; ++r)
        pw[(quad * 4 + r) * PPAD + nt * 16 + l15] = (unsigned short)f2bf(aq[r]);
    }
    lds_fence();
    bf16x8 qa[2];
#pragma unroll
    for (int c = 0; c < 2; ++c)
      qa[c] = *(const bf16x8*)(pw + l15 * PPAD + c * 32 + quad * 8);
    lds_fence();   // reads drained before the key loop reuses pw

    f32x4 o[4];
    float m[4], lsum[4];
#pragma unroll
    for (int nt = 0; nt < 4; ++nt) o[nt] = (f32x4){0.f, 0.f, 0.f, 0.f};
#pragma unroll
    for (int r = 0; r < 4; ++r) { m[r] = -1e30f; lsum[r] = 0.f; }

    const int nfull = q0 >> 5;   // number of fully-unmasked 32-key tiles
#pragma unroll 1
    for (int kt = 0; kt <= nfull; ++kt) {
      const int kb = kt * 32;
      // S tile (16 rows x 32 keys) = Q . K^T : K A-layout frag == B-frag of K^T
      f32x4 s0 = {0.f, 0.f, 0.f, 0.f};
      f32x4 s1 = {0.f, 0.f, 0.f, 0.f};
#pragma unroll
      for (int c = 0; c < 2; ++c) {
        bf16x8 kf0 = *(const bf16x8*)(ldsK + (kb + l15) * KPAD + c * 32 + quad * 8);
        bf16x8 kf1 = *(const bf16x8*)(ldsK + (kb + 16 + l15) * KPAD + c * 32 + quad * 8);
        s0 = __builtin_amdgcn_mfma_f32_16x16x32_bf16(qa[c], kf0, s0, 0, 0, 0);
        s1 = __builtin_amdgcn_mfma_f32_16x16x32_bf16(qa[c], kf1, s1, 0, 0, 0);
      }
      if (kt == nfull) {   // causal mask, only on the diagonal tile
        const int qr = q0 + quad * 4;
#pragma unroll
        for (int r = 0; r < 4; ++r) {
          if (kb + l15 > qr + r)      s0[r] = -1e30f;
          if (kb + 16 + l15 > qr + r) s1[r] = -1e30f;
        }
      }
      // online softmax; rows live in 16-lane quad groups -> 4-step xor reduce
      float al[4];
#pragma unroll
      for (int r = 0; r < 4; ++r) {
        float t = fmaxf(s0[r], s1[r]);
        t = fmaxf(t, __shfl_xor(t, 1));
        t = fmaxf(t, __shfl_xor(t, 2));
        t = fmaxf(t, __shfl_xor(t, 4));
        t = fmaxf(t, __shfl_xor(t, 8));
        const float mn = fmaxf(m[r], t);
        al[r] = __expf(m[r] - mn);
        m[r]  = mn;
        s0[r] = __expf(s0[r] - mn);
        s1[r] = __expf(s1[r] - mn);
        float rs = s0[r] + s1[r];
        rs += __shfl_xor(rs, 1);
        rs += __shfl_xor(rs, 2);
        rs += __shfl_xor(rs, 4);
        rs += __shfl_xor(rs, 8);
        lsum[r] = lsum[r] * al[r] + rs;
      }
#pragma unroll
      for (int nt = 0; nt < 4; ++nt)
#pragma unroll
        for (int r = 0; r < 4; ++r) o[nt][r] *= al[r];

      // P: C-layout -> A-layout via per-wave LDS buffer (16x32 bf16)
#pragma unroll
      for (int r = 0; r < 4; ++r) {
        pw[(quad * 4 + r) * PPAD + l15]      = (unsigned short)f2bf(s0[r]);
        pw[(quad * 4 + r) * PPAD + 16 + l15] = (unsigned short)f2bf(s1[r]);
      }
      lds_fence();
      bf16x8 pa = *(const bf16x8*)(pw + l15 * PPAD + quad * 8);
      // O += P . V : B-frag of V from transposed Vt rows (contiguous 16B)
#pragma unroll
      for (int nt = 0; nt < 4; ++nt) {
        bf16x8 vf = *(const bf16x8*)(ldsV + (nt * 16 + l15) * VPAD + kb + quad * 8);
        o[nt] = __builtin_amdgcn_mfma_f32_16x16x32_bf16(pa, vf, o[nt], 0, 0, 0);
      }
      lds_fence();   // pa/vf reads drained before next iteration overwrites pw
    }

    // epilogue: out = O / l  (fp32, coalesced 64B per 16-lane group)
    float inv[4];
#pragma unroll
    for (int r = 0; r < 4; ++r) inv[r] = 1.0f / lsum[r];
#pragma unroll
    for (int nt = 0; nt < 4; ++nt)
#pragma unroll
      for (int r = 0; r < 4; ++r) {
        const int row = q0 + quad * 4 + r;
        outb[row * HSZ + nt * 16 + l15] = o[nt][r] * inv[r];
      }
  }
}

extern "C" void kernel_launch(void* const* d_in, const int* in_sizes, int n_in,
                              void* d_out, int out_size, void* d_ws, size_t ws_size,
                              hipStream_t stream) {
  const float* x  = (const float*)d_in[0];
  const float* wk = (const float*)d_in[1];   // w_key
  const float* wq = (const float*)d_in[2];   // w_query
  const float* wv = (const float*)d_in[3];   // w_value
  (void)in_sizes; (void)n_in; (void)out_size; (void)d_ws; (void)ws_size;
  attn_fused<<<BATCH, 512, 0, stream>>>(x, wk, wq, wv, (float*)d_out);
}